// Round 8
// baseline (81806.152 us; speedup 1.0000x reference)
//
#include <hip/hip_runtime.h>
#include <hip/hip_bf16.h>
#include <math.h>

// WaveNet autoregressive generation, MI355X, fp32 (argmax feedback forbids
// low-precision; no fp32 MFMA on CDNA4 -> vector ALU kernel).
//
// One WG of 512 threads (8 waves, 2/SIMD) per batch element.
// R7 post-mortem: NT=1024 (launch_bounds cap 128 VGPR -> allocator chose 64)
// caused register SPILLS: +3.2GB fetch / +174MB write of scratch traffic on
// the critical path -> 54ms regardless of coalescing. NT=512 lifts the VGPR
// cap to 256 (2 waves/SIMD) while keeping 2x the latency-hiding of the
// 14.1ms round-1 kernel.
// Structure kept from R7: depth-slice index is WAVE-uniform (coalesced 256B
// weight rows), lane = column; queue pops prefetched one step ahead and
// hidden under the output head; pushes batched there too (xHist tape);
// 3 barriers/layer; skip partials reduced once per step.

#define NL 30
#define NC 64
#define NS 256
#define NV 256
#define NB 128
#define QTOT 3069   // sum of dilations: 3 * (2^10 - 1)
#define NT 512

// Per-batch dilation queues (~100.6 MB) in static device memory. Slot for
// layer l is written at step t and read at step t+d; reads gated by (t >= d)
// so stale cross-launch contents are never observed (re-poison safe).
__device__ float g_queues[(size_t)NB * QTOT * NC];

__device__ __forceinline__ void layer_params(int l, int& d, int& qo) {
  const int a = (l >= 20) ? 2 : ((l >= 10) ? 1 : 0);
  const int bb = l - a * 10;
  d = 1 << bb;
  qo = a * 1023 + (d - 1);
}

__global__ __launch_bounds__(NT, 1)
void wavenet_gen_kernel(const int* __restrict__ seed,
                        const float* __restrict__ emb,     // (V, C)
                        const float* __restrict__ kern,    // (L, 2, C, 2C)
                        const float* __restrict__ cbias,   // (L, 2C)
                        const float* __restrict__ resw,    // (L, C, C)
                        const float* __restrict__ resb,    // (L, C)
                        const float* __restrict__ skipw,   // (L, C, S)
                        const float* __restrict__ skipb,   // (L, S)
                        const float* __restrict__ w0,      // (S, V)
                        const float* __restrict__ b0,      // (V)
                        const float* __restrict__ w1,      // (V, V)
                        const float* __restrict__ b1,      // (V)
                        const int* __restrict__ pT,
                        float* __restrict__ out)
{
  const int b    = blockIdx.x;
  const int t_   = threadIdx.x;
  const int T    = pT[0];
  const int lane = t_ & 63;
  const int w    = t_ >> 6;          // wave 0..7

  // conv: wave -> (half, col-half, depth-slice of 2); lane -> column
  const int cv_half = w & 1;
  const int cv_col  = ((w >> 1) & 1) * 64 + lane;   // 0..127
  const int cv_p    = w >> 2;                        // 0..1
  // skip/head: wave -> (depth-slice of 2, col-chunk); lane -> column
  const int sk_p    = w >> 2;                        // 0..1
  const int sk_j    = (w & 3) * 64 + lane;           // 0..255

  __shared__ float sxlAll[NL][NC];   // prefetched x_last per layer
  __shared__ float xHist[NL][NC];    // layer-input tape (queue push source)
  __shared__ float hpc[2][2][2 * NC];// conv partials [slice][half][col]
  __shared__ float sg[NC];           // gated activation
  __shared__ float sp[2][NS];        // skip partials (reduced once per step)
  __shared__ float sskip[NS];
  __shared__ float hh[2][NV];        // head partials (both matmuls)
  __shared__ float sh0[NV];
  __shared__ float rv[4];
  __shared__ int   ri[4];
  __shared__ int   snext;

  // step-0 pops are all zeros (t=0 < d for every layer); NL*NC = 1920
  for (int k = t_; k < NL * NC; k += NT) ((float*)sxlAll)[k] = 0.f;
  if (t_ < NC) xHist[0][t_] = emb[(size_t)seed[b] * NC + t_];
  __syncthreads();

  float* __restrict__ q = g_queues + (size_t)b * QTOT * NC;
  const size_t logits_base = (size_t)NB * (size_t)T;

  for (int t = 0; t < T; ++t) {
    float skipacc = 0.f;   // private: depth-slice sk_p of skip column sk_j

    for (int i = 0; i < NL; ++i) {
      // ---- conv partials: lane=col (256B coalesced), wave-uniform slice ----
      {
        const float* __restrict__ W =
            kern + ((size_t)(i * 2 + cv_half)) * (NC * 2 * NC) + cv_col;
        const float* __restrict__ xv = cv_half ? xHist[i] : sxlAll[i];
        float acc = 0.f;
#pragma unroll
        for (int cc = 0; cc < 32; ++cc) {
          const int c = cv_p * 32 + cc;                 // wave-uniform row
          acc = fmaf(xv[c], W[(size_t)c * (2 * NC)], acc);
        }
        hpc[cv_p][cv_half][cv_col] = acc;
      }
      __syncthreads();

      // ---- gate: sum 4 partials per column, tanh*sigmoid (1 wave) ----
      if (t_ < NC) {
        float ha = cbias[i * 2 * NC + t_];
        float hb = cbias[i * 2 * NC + NC + t_];
#pragma unroll
        for (int p = 0; p < 2; ++p) {
          ha += hpc[p][0][t_]      + hpc[p][1][t_];
          hb += hpc[p][0][NC + t_] + hpc[p][1][NC + t_];
        }
        sg[t_] = tanhf(ha) * (1.f / (1.f + expf(-hb)));
      }
      __syncthreads();

      // ---- skip partial (all 8 waves, coalesced, private accumulate) ----
      {
        const float* __restrict__ SW = skipw + (size_t)i * NC * NS + sk_j;
        float acc = 0.f;
#pragma unroll
        for (int cc = 0; cc < 32; ++cc) {
          const int c = sk_p * 32 + cc;
          acc = fmaf(sg[c], SW[(size_t)c * NS], acc);
        }
        skipacc += acc;
        if (sk_p == 0) skipacc += skipb[i * NS + sk_j];
      }
      // ---- residual (waves 0..3): 16 cols x 4 in-wave depth slices ----
      if (w < 4 && i < NL - 1) {   // layer 29's x output is dead
        const int rcol = w * 16 + (lane & 15);
        const int rp   = lane >> 4;
        const float* __restrict__ RW = resw + (size_t)i * NC * NC + rcol;
        float racc = 0.f;
#pragma unroll
        for (int cc = 0; cc < 16; ++cc) {
          const int c = rp * 16 + cc;
          racc = fmaf(sg[c], RW[(size_t)c * NC], racc);
        }
        racc += __shfl_xor(racc, 16);
        racc += __shfl_xor(racc, 32);
        if (lane < 16)
          xHist[i + 1][rcol] = xHist[i][rcol] + racc + resb[i * NC + rcol];
      }
      __syncthreads();
    }

    // ================= head (queue traffic overlapped) =================
    // H0: park skip partials; prefetch step-(t+1) pops; push step-t values.
    // Wave w owns layers w, w+8, w+16, w+24 (lane -> channel).
    sp[sk_p][sk_j] = skipacc;
    const int tp = t + 1;
    float rQ[4] = {0.f, 0.f, 0.f, 0.f};
    {
#pragma unroll
      for (int k = 0; k < 4; ++k) {          // pops first (no alias waits)
        const int l = w + 8 * k;
        if (l < NL) {
          int d, qo; layer_params(l, d, qo);
          if (d > 1 && tp >= d)
            rQ[k] = q[(size_t)(qo + (tp & (d - 1))) * NC + lane];
        }
      }
#pragma unroll
      for (int k = 0; k < 4; ++k) {          // then pushes (d=1: LDS bypass)
        const int l = w + 8 * k;
        if (l < NL) {
          int d, qo; layer_params(l, d, qo);
          const float xv = xHist[l][lane];
          if (d == 1) rQ[k] = xv;
          else q[(size_t)(qo + (t & (d - 1))) * NC + lane] = xv;
        }
      }
    }
    __syncthreads();

    // H1: finalize skip
    if (t_ < NS) sskip[t_] = fmaxf(sp[0][t_] + sp[1][t_], 0.f);
    __syncthreads();

    // H2: h0 partials (depth 256, 2 wave-uniform slices of 128)
    {
      const float* __restrict__ W = w0 + sk_j;
      float acc = 0.f;
#pragma unroll 16
      for (int cc = 0; cc < 128; ++cc) {
        const int c = sk_p * 128 + cc;
        acc = fmaf(sskip[c], W[(size_t)c * NV], acc);
      }
      hh[sk_p][sk_j] = acc;
    }
    __syncthreads();

    // H3: finalize h0
    if (t_ < NV) sh0[t_] = fmaxf(hh[0][t_] + hh[1][t_] + b0[t_], 0.f);
    __syncthreads();

    // H4: logits partials (reuse hh)
    {
      const float* __restrict__ W = w1 + sk_j;
      float acc = 0.f;
#pragma unroll 16
      for (int cc = 0; cc < 128; ++cc) {
        const int c = sk_p * 128 + cc;
        acc = fmaf(sh0[c], W[(size_t)c * NV], acc);
      }
      hh[sk_p][sk_j] = acc;
    }
    __syncthreads();

    // H5: finalize logits, store, argmax (first-max semantics)
    if (t_ < NV) {
      const float lg = hh[0][t_] + hh[1][t_] + b1[t_];
      out[logits_base + ((size_t)b * T + t) * NV + t_] = lg;
      float v = lg; int ix = t_;
#pragma unroll
      for (int o = 32; o > 0; o >>= 1) {
        const float ov = __shfl_down(v, o);
        const int   oi = __shfl_down(ix, o);
        if (ov > v || (ov == v && oi < ix)) { v = ov; ix = oi; }
      }
      if (lane == 0) { rv[w] = v; ri[w] = ix; }
    }
    __syncthreads();
    if (t_ == 0) {
      float bv = rv[0]; int bi = ri[0];
#pragma unroll
      for (int k = 1; k < 4; ++k)
        if (rv[k] > bv || (rv[k] == bv && ri[k] < bi)) { bv = rv[k]; bi = ri[k]; }
      snext = bi;
      out[(size_t)b * T + t] = (float)bi;
    }
    __syncthreads();

    // H6: commit prefetched pops; embedding feedback
#pragma unroll
    for (int k = 0; k < 4; ++k) {
      const int l = w + 8 * k;
      if (l < NL) sxlAll[l][lane] = rQ[k];
    }
    if (t_ < NC) xHist[0][t_] = emb[(size_t)snext * NC + t_];
    __syncthreads();
  }
}

extern "C" void kernel_launch(void* const* d_in, const int* in_sizes, int n_in,
                              void* d_out, int out_size, void* d_ws, size_t ws_size,
                              hipStream_t stream) {
  (void)in_sizes; (void)n_in; (void)out_size; (void)d_ws; (void)ws_size;
  wavenet_gen_kernel<<<NB, NT, 0, stream>>>(
      (const int*)d_in[0],   (const float*)d_in[1], (const float*)d_in[2],
      (const float*)d_in[3], (const float*)d_in[4], (const float*)d_in[5],
      (const float*)d_in[6], (const float*)d_in[7], (const float*)d_in[8],
      (const float*)d_in[9], (const float*)d_in[10], (const float*)d_in[11],
      (const int*)d_in[12],  (float*)d_out);
}

// Round 10
// 12567.735 us; speedup vs baseline: 6.5092x; 6.5092x over previous
//
#include <hip/hip_runtime.h>
#include <hip/hip_bf16.h>
#include <math.h>

// WaveNet autoregressive generation, MI355X, fp32 (argmax feedback forbids
// low precision; no fp32 MFMA on CDNA4 -> vector ALU kernel).
//
// One WG of 320 threads (5 waves) per batch element; latency-bound on the
// per-element serial chain. This round attacks the chain itself:
//  - 2 barriers/layer (gate barrier removed: every wave computes the 64-wide
//    gate redundantly, lane c holds sg_c; dots consume it via __shfl
//    broadcast with compile-time lane -> v_readlane, no LDS round trip).
//  - gate uses __expf identity (parallel, ~40cy) instead of serial 1-wave
//    libm tanhf/expf (~400cy).
//  - B phase exactly balanced: skip(256 cols) + res(64 cols) = 5 waves.
//  - wave 4 = queue wave: pushes layer i, issues pop for layer i+2 into a
//    register, commits pop i+1 to LDS in B(i) -> pop latency covered by a
//    full layer; step-boundary pops (layers 0,1 of t+1) issue in the head.
//  - d=1 hazard check: pop(t,0) is issued during step t-1's head, long after
//    push(t-1,0) at A(0) of step t-1; same-thread same-address ordering.

#define NL 30
#define NC 64
#define NS 256
#define NV 256
#define NB 128
#define QTOT 3069   // sum of dilations: 3 * (2^10 - 1)
#define NT 320

// Per-batch dilation queues (~100.6 MB) in static device memory. Slot for
// layer l is written at step t and read at step t+d; reads gated by (t >= d)
// so stale cross-launch contents are never observed (re-poison safe).
__device__ float g_queues[(size_t)NB * QTOT * NC];

__device__ __forceinline__ void layer_params(int l, int& d, int& qo) {
  const int a = (l >= 20) ? 2 : ((l >= 10) ? 1 : 0);
  const int bb = l - a * 10;
  d = 1 << bb;
  qo = a * 1023 + (d - 1);
}

// tanh(a)*sigmoid(b) = (e^{2a}-1) / ((e^{2a}+1)*(1+e^{-b}))
__device__ __forceinline__ float gate_fast(float ha, float hb) {
  const float e2a = __expf(2.f * ha);
  const float enb = __expf(-hb);
  return (e2a - 1.f) / ((e2a + 1.f) * (1.f + enb));
}

__global__ __launch_bounds__(NT, 1)
void wavenet_gen_kernel(const int* __restrict__ seed,
                        const float* __restrict__ emb,     // (V, C)
                        const float* __restrict__ kern,    // (L, 2, C, 2C)
                        const float* __restrict__ cbias,   // (L, 2C)
                        const float* __restrict__ resw,    // (L, C, C)
                        const float* __restrict__ resb,    // (L, C)
                        const float* __restrict__ skipw,   // (L, C, S)
                        const float* __restrict__ skipb,   // (L, S)
                        const float* __restrict__ w0,      // (S, V)
                        const float* __restrict__ b0,      // (V)
                        const float* __restrict__ w1,      // (V, V)
                        const float* __restrict__ b1,      // (V)
                        const int* __restrict__ pT,
                        float* __restrict__ out)
{
  const int b    = blockIdx.x;
  const int t_   = threadIdx.x;
  const int T    = pT[0];
  const int lane = t_ & 63;
  const int w    = t_ >> 6;          // wave 0..4

  __shared__ float xbuf[2][NC];      // layer input x (double-buffered)
  __shared__ float sxl[2][NC];       // popped x_last (double-buffered)
  __shared__ float hp[2][2 * NC];    // conv partials [which-input][col 0..127]
  __shared__ float sskip[NS];
  __shared__ float sh0[NV];
  __shared__ float rv[4];
  __shared__ int   ri[4];
  __shared__ int   snext;

  if (t_ < NC) {
    sxl[0][t_] = 0.f;                // step-0 pops are zero (t=0 < d)
    sxl[1][t_] = 0.f;
    xbuf[0][t_] = emb[(size_t)seed[b] * NC + t_];
  }
  float rP0 = 0.f, rP1 = 0.f;        // in-flight pop regs (wave 4)
  __syncthreads();

  float* __restrict__ q = g_queues + (size_t)b * QTOT * NC;
  const size_t logits_base = (size_t)NB * (size_t)T;

  for (int t = 0; t < T; ++t) {
    float skipacc = 0.f;             // waves 0..3: skip col t_ accumulator

    for (int i = 0; i < NL; ++i) {
      const int cb = i & 1;

      // ---------------- phase A: conv (waves 0-3) | queue (wave 4) --------
      if (w < 4) {
        const int half = w & 1;                     // 0: x_last op, 1: x op
        const int col  = ((w >> 1) << 6) + lane;    // 0..127
        const float* __restrict__ W =
            kern + ((size_t)(i * 2 + half)) * (NC * 2 * NC) + col;
        const float* __restrict__ xv = half ? xbuf[cb] : sxl[cb];
        float a0 = 0.f, a1 = 0.f;
#pragma unroll
        for (int c = 0; c < NC; c += 2) {
          a0 = fmaf(xv[c],     W[(size_t)c * (2 * NC)],       a0);
          a1 = fmaf(xv[c + 1], W[(size_t)(c + 1) * (2 * NC)], a1);
        }
        hp[half][col] = a0 + a1;
      } else {
        // push layer i's input (value from B(i-1) / head, barrier passed)
        int d, qo; layer_params(i, d, qo);
        q[(size_t)(qo + (t & (d - 1))) * NC + lane] = xbuf[cb][lane];
        // issue pop for layer i+2 (this step) into rP[i&1]
        const int j = i + 2;
        if (j < NL) {
          int dj, qj; layer_params(j, dj, qj);
          float v = 0.f;
          if (t >= dj) v = q[(size_t)(qj + (t & (dj - 1))) * NC + lane];
          if (cb) rP1 = v; else rP0 = v;   // j&1 == i&1
        }
      }
      __syncthreads();

      // ---------------- phase B: gate (all waves, redundant) + dots -------
      const float ha = hp[0][lane] + hp[1][lane] + cbias[i * 2 * NC + lane];
      const float hb = hp[0][NC + lane] + hp[1][NC + lane]
                     + cbias[i * 2 * NC + NC + lane];
      const float sgv = gate_fast(ha, hb);   // lane c holds sg[c]

      if (w < 4) {
        // skip: col t_ (coalesced), depth 64 via readlane broadcast
        const float* __restrict__ SW = skipw + (size_t)i * NC * NS + t_;
        float a0 = 0.f, a1 = 0.f;
#pragma unroll
        for (int c = 0; c < NC; c += 2) {
          a0 = fmaf(__shfl(sgv, c),     SW[(size_t)c * NS],       a0);
          a1 = fmaf(__shfl(sgv, c + 1), SW[(size_t)(c + 1) * NS], a1);
        }
        skipacc += a0 + a1 + skipb[i * NS + t_];
      } else {
        if (i < NL - 1) {   // layer 29's x output is dead
          const float* __restrict__ RW = resw + (size_t)i * NC * NC + lane;
          float a0 = 0.f, a1 = 0.f;
#pragma unroll
          for (int c = 0; c < NC; c += 2) {
            a0 = fmaf(__shfl(sgv, c),     RW[(size_t)c * NC],       a0);
            a1 = fmaf(__shfl(sgv, c + 1), RW[(size_t)(c + 1) * NC], a1);
          }
          xbuf[cb ^ 1][lane] = xbuf[cb][lane] + a0 + a1 + resb[i * NC + lane];
          // commit pop for layer i+1 (issued at A(i-1), reg rP[(i+1)&1])
          sxl[cb ^ 1][lane] = (cb ^ 1) ? rP1 : rP0;
        }
      }
      __syncthreads();
    }

    // ======================= output head =======================
    // H1: finalize skip | wave 4: issue pops for (t+1, layers 0 and 1)
    if (t_ < NS) {
      sskip[t_] = fmaxf(skipacc, 0.f);
    } else {
      { int d, qo; layer_params(0, d, qo);
        rP0 = (t + 1 >= d) ? q[(size_t)(qo + ((t + 1) & (d - 1))) * NC + lane] : 0.f; }
      { int d, qo; layer_params(1, d, qo);
        rP1 = (t + 1 >= d) ? q[(size_t)(qo + ((t + 1) & (d - 1))) * NC + lane] : 0.f; }
    }
    __syncthreads();

    // H2: h0 = relu(skip @ w0 + b0), 256-deep dot, col = t_
    if (t_ < NV) {
      const float* __restrict__ W = w0 + t_;
      float a0 = 0.f, a1 = 0.f;
#pragma unroll 8
      for (int s = 0; s < NS; s += 2) {
        a0 = fmaf(sskip[s],     W[(size_t)s * NV],       a0);
        a1 = fmaf(sskip[s + 1], W[(size_t)(s + 1) * NV], a1);
      }
      sh0[t_] = fmaxf(a0 + a1 + b0[t_], 0.f);
    }
    __syncthreads();

    // H3: logits + store + wave-level argmax (first-max semantics)
    if (t_ < NV) {
      const float* __restrict__ W = w1 + t_;
      float a0 = 0.f, a1 = 0.f;
#pragma unroll 8
      for (int s = 0; s < NV; s += 2) {
        a0 = fmaf(sh0[s],     W[(size_t)s * NV],       a0);
        a1 = fmaf(sh0[s + 1], W[(size_t)(s + 1) * NV], a1);
      }
      const float lg = a0 + a1 + b1[t_];
      out[logits_base + ((size_t)b * T + t) * NV + t_] = lg;
      float v = lg; int ix = t_;
#pragma unroll
      for (int o = 32; o > 0; o >>= 1) {
        const float ov = __shfl_down(v, o);
        const int   oi = __shfl_down(ix, o);
        if (ov > v || (ov == v && oi < ix)) { v = ov; ix = oi; }
      }
      if (lane == 0) { rv[w] = v; ri[w] = ix; }
    }
    __syncthreads();

    // H4: final argmax | wave 4: commit pop(t+1, layer 0)
    if (t_ == 0) {
      float bv = rv[0]; int bi = ri[0];
#pragma unroll
      for (int k = 1; k < 4; ++k)
        if (rv[k] > bv || (rv[k] == bv && ri[k] < bi)) { bv = rv[k]; bi = ri[k]; }
      snext = bi;
      out[(size_t)b * T + t] = (float)bi;   // samples written as float
    }
    if (w == 4) sxl[0][lane] = rP0;   // pop(t+1,1) stays in rP1 -> B(0) commit
    __syncthreads();

    // H5: embedding feedback
    if (t_ < NC) xbuf[0][t_] = emb[(size_t)snext * NC + t_];
    __syncthreads();
  }
}

extern "C" void kernel_launch(void* const* d_in, const int* in_sizes, int n_in,
                              void* d_out, int out_size, void* d_ws, size_t ws_size,
                              hipStream_t stream) {
  (void)in_sizes; (void)n_in; (void)out_size; (void)d_ws; (void)ws_size;
  wavenet_gen_kernel<<<NB, NT, 0, stream>>>(
      (const int*)d_in[0],   (const float*)d_in[1], (const float*)d_in[2],
      (const float*)d_in[3], (const float*)d_in[4], (const float*)d_in[5],
      (const float*)d_in[6], (const float*)d_in[7], (const float*)d_in[8],
      (const float*)d_in[9], (const float*)d_in[10], (const float*)d_in[11],
      (const int*)d_in[12],  (float*)d_out);
}